// Round 2
// baseline (1953.051 us; speedup 1.0000x reference)
//
#include <hip/hip_runtime.h>
#include <hip/hip_bf16.h>

// ActionSTGCN on MI355X — round 2: fp32 I/O (per reference dtypes), bf16
// intermediate activations in ws, fp32 math throughout.
//
// Layout trick: temporal conv (9,1) over (T,V) with V innermost == 1D conv with
// dilation 33 over the flat 8448-elem (t*33+v) plane, incl. zero padding
// (plane over/underflow == t out of range, v never wraps). T*V = 256*33 = 8448
// = 33 blocks of 256 threads exactly.

typedef __hip_bfloat16 bf16;

#define TV 8448      // T*V = 256*33
#define NB 64        // batch
#define EPSBN 1e-5f

__device__ __forceinline__ float cvt(bf16 x) { return __bfloat162float(x); }

// ---------------- workspace layout (fp32 param region, then 3 bf16 bufs) ----
constexpr int P_A     = 0;                 // 33*33 adjacency, fp32
constexpr int P_INV0  = P_A + 1089;        // 198 input-BN scale (c*33+v)
constexpr int P_BIAS0 = P_INV0 + 198;      // 198 input-BN shift
// block0 (ci=6, co=32)
constexpr int P_PW0   = P_BIAS0 + 198;     // 192  proj W, [c*CO+o]
constexpr int P_PB0   = P_PW0 + 192;       // 32
constexpr int P_I1_0  = P_PB0 + 32;        // 32   bn1 scale
constexpr int P_B1_0  = P_I1_0 + 32;       // 32   bn1 shift
constexpr int P_WT0   = P_B1_0 + 32;       // 9216 tcn W, [(c*9+k)*CO+o]
constexpr int P_I2_0  = P_WT0 + 9216;      // 32   bn2 scale
constexpr int P_B2_0  = P_I2_0 + 32;       // 32   bn2 shift (tcn bias folded)
constexpr int P_RW0   = P_B2_0 + 32;       // 192  res W, [o*CI+c]
constexpr int P_RB0   = P_RW0 + 192;       // 32
// block1 (ci=32, co=64)
constexpr int P_PW1   = P_RB0 + 32;        // 2048
constexpr int P_PB1   = P_PW1 + 2048;
constexpr int P_I1_1  = P_PB1 + 64;
constexpr int P_B1_1  = P_I1_1 + 64;
constexpr int P_WT1   = P_B1_1 + 64;       // 36864
constexpr int P_I2_1  = P_WT1 + 36864;
constexpr int P_B2_1  = P_I2_1 + 64;
constexpr int P_RW1   = P_B2_1 + 64;       // 2048
constexpr int P_RB1   = P_RW1 + 2048;
// block2 (ci=64, co=64, identity residual)
constexpr int P_PW2   = P_RB1 + 64;        // 4096
constexpr int P_PB2   = P_PW2 + 4096;
constexpr int P_I1_2  = P_PB2 + 64;
constexpr int P_B1_2  = P_I1_2 + 64;
constexpr int P_WT2   = P_B1_2 + 64;       // 36864
constexpr int P_I2_2  = P_WT2 + 36864;
constexpr int P_B2_2  = P_I2_2 + 64;
// fc + feat scratch
constexpr int P_FCW   = P_B2_2 + 64;       // 6400  [n*64+o]
constexpr int P_FCB   = P_FCW + 6400;      // 100
constexpr int P_FEAT  = P_FCB + 100;       // 4096  pooled features fp32
constexpr int P_END   = P_FEAT + 4096;
constexpr size_t PARAM_BYTES = ((size_t)P_END * 4 + 255) / 256 * 256;
constexpr size_t BUF_ELEMS   = (size_t)NB * 64 * TV;   // 34,603,008 bf16

// ---------------- prep: fuse/transpose params into ws (fp32) ----------------
struct Ptrs { const float* p[48]; };

__device__ void prep_smalls(const Ptrs& in, float* ws, int F, int CI, int CO,
                            int pwO, int pbO, int i1O, int b1O, int i2O, int b2O,
                            int rwO, int rbO, bool has_res) {
  const int tid = threadIdx.x;
  const float* pw = in.p[F];
  for (int i = tid; i < CI * CO; i += 256) {        // pwT[c*CO+o] = pw[o*CI+c]
    int c = i / CO, o = i - c * CO;
    ws[pwO + i] = pw[o * CI + c];
  }
  for (int i = tid; i < CO; i += 256) {
    ws[pbO + i] = in.p[F + 1][i];
    float g1 = in.p[F + 2][i], b1 = in.p[F + 3][i];
    float m1 = in.p[F + 4][i], v1 = in.p[F + 5][i];
    float inv1 = g1 / sqrtf(v1 + EPSBN);
    ws[i1O + i] = inv1; ws[b1O + i] = b1 - m1 * inv1;
    float tb = in.p[F + 7][i];
    float g2 = in.p[F + 8][i], b2 = in.p[F + 9][i];
    float m2 = in.p[F + 10][i], v2 = in.p[F + 11][i];
    float inv2 = g2 / sqrtf(v2 + EPSBN);
    ws[i2O + i] = inv2; ws[b2O + i] = tb * inv2 + b2 - m2 * inv2;  // bn2(y+tb)
  }
  if (has_res) {
    const float* rw = in.p[F + 12];
    for (int i = tid; i < CO * CI; i += 256) ws[rwO + i] = rw[i];
    for (int i = tid; i < CO; i += 256) ws[rbO + i] = in.p[F + 13][i];
  }
}

__device__ void prep_wt(const float* tw, float* dst, int CO) {
  const int tid = threadIdx.x;
  int n = CO * CO * 9;
  for (int i = tid; i < n; i += 256) {              // wT[(c*9+k)*CO+o] = tw[(o*CO+c)*9+k]
    int o = i % CO, ck = i / CO;
    int c = ck / 9, k = ck - c * 9;
    dst[i] = tw[(o * CO + c) * 9 + k];
  }
}

__global__ __launch_bounds__(256) void prep_kernel(Ptrs in, float* __restrict__ ws) {
  const int tid = threadIdx.x;
  switch (blockIdx.x) {
    case 0: {
      for (int i = tid; i < 1089; i += 256) ws[P_A + i] = in.p[1][i];
      for (int i = tid; i < 198; i += 256) {
        float g = in.p[2][i], b = in.p[3][i];
        float m = in.p[4][i], v = in.p[5][i];
        float inv = g / sqrtf(v + EPSBN);
        ws[P_INV0 + i] = inv; ws[P_BIAS0 + i] = b - m * inv;
      }
      for (int i = tid; i < 6400; i += 256) ws[P_FCW + i] = in.p[46][i];
      for (int i = tid; i < 100; i += 256) ws[P_FCB + i] = in.p[47][i];
      break;
    }
    case 1: prep_smalls(in, ws, 6, 6, 32, P_PW0, P_PB0, P_I1_0, P_B1_0, P_I2_0, P_B2_0, P_RW0, P_RB0, true); break;
    case 2: prep_wt(in.p[12], ws + P_WT0, 32); break;
    case 3: prep_smalls(in, ws, 20, 32, 64, P_PW1, P_PB1, P_I1_1, P_B1_1, P_I2_1, P_B2_1, P_RW1, P_RB1, true); break;
    case 4: prep_wt(in.p[26], ws + P_WT1, 64); break;
    case 5: prep_smalls(in, ws, 34, 64, 64, P_PW2, P_PB2, P_I1_2, P_B1_2, P_I2_2, P_B2_2, 0, 0, false); break;
    case 6: prep_wt(in.p[40], ws + P_WT2, 64); break;
  }
}

// ---------------- K1a: 1x1 projection (block0 fuses input-BN; fp32 input) ---
// grid (33, B), 256 thr. Thread owns flat pixel p; acc[CO] regs; weights are
// thread-uniform -> s_load. Global reads/writes fully coalesced.
template <int CI, int CO>
__global__ __launch_bounds__(256) void k1a_in(const float* __restrict__ in,
                                              const float* __restrict__ ws,
                                              bf16* __restrict__ zout,
                                              int pwO, int pbO) {
  const int tid = threadIdx.x;
  const int p = blockIdx.x * 256 + tid;
  const int b = blockIdx.y;
  const int v = p % 33;
  const float* pwT = ws + pwO;
  const float* pb  = ws + pbO;
  float acc[CO];
#pragma unroll
  for (int o = 0; o < CO; o++) acc[o] = pb[o];
  for (int c = 0; c < CI; c++) {
    float hv = in[((size_t)(b * CI + c)) * TV + p];
    hv = fmaf(hv, ws[P_INV0 + c * 33 + v], ws[P_BIAS0 + c * 33 + v]);
    const float* w = pwT + c * CO;
#pragma unroll
    for (int o = 0; o < CO; o++) acc[o] = fmaf(w[o], hv, acc[o]);
  }
#pragma unroll
  for (int o = 0; o < CO; o++)
    zout[((size_t)(b * CO + o)) * TV + p] = __float2bfloat16(acc[o]);
}

// Same, bf16 input (blocks 1,2).
template <int CI, int CO>
__global__ __launch_bounds__(256) void k1a(const bf16* __restrict__ in,
                                           const float* __restrict__ ws,
                                           bf16* __restrict__ zout,
                                           int pwO, int pbO) {
  const int tid = threadIdx.x;
  const int p = blockIdx.x * 256 + tid;
  const int b = blockIdx.y;
  const float* pwT = ws + pwO;
  const float* pb  = ws + pbO;
  float acc[CO];
#pragma unroll
  for (int o = 0; o < CO; o++) acc[o] = pb[o];
  for (int c = 0; c < CI; c++) {
    float hv = cvt(in[((size_t)(b * CI + c)) * TV + p]);
    const float* w = pwT + c * CO;
#pragma unroll
    for (int o = 0; o < CO; o++) acc[o] = fmaf(w[o], hv, acc[o]);
  }
#pragma unroll
  for (int o = 0; o < CO; o++)
    zout[((size_t)(b * CO + o)) * TV + p] = __float2bfloat16(acc[o]);
}

// ---------------- K1b: adjacency mix over joints + BN1 + ReLU ---------------
// grid = B*CO blocks (one (b,o) plane each, t = tid), 256 thr. Row in LDS,
// A columns wave-uniform -> s_load; o block-uniform -> scalar BN params.
__global__ __launch_bounds__(256) void k1b(const bf16* __restrict__ z,
                                           const float* __restrict__ ws,
                                           bf16* __restrict__ y3,
                                           int i1O, int b1O, int coMask) {
  __shared__ float sz[TV];
  const int tid = threadIdx.x;
  const int n = blockIdx.x;                 // n = b*CO + o
  const size_t base = (size_t)n * TV;
  for (int i = tid; i < TV; i += 256) sz[i] = cvt(z[base + i]);
  __syncthreads();
  const float* pA = ws + P_A;
  float acc[33];
#pragma unroll
  for (int w = 0; w < 33; w++) acc[w] = 0.f;
  for (int v = 0; v < 33; v++) {
    float zv = sz[tid * 33 + v];            // own row only; 2-way bank alias = free
    const float* Ar = pA + v * 33;          // wave-uniform -> s_load
#pragma unroll
    for (int w = 0; w < 33; w++) acc[w] = fmaf(Ar[w], zv, acc[w]);
  }
  const int o = n & coMask;
  const float inv1 = ws[i1O + o];
  const float sh1  = ws[b1O + o];
#pragma unroll
  for (int w = 0; w < 33; w++) {
    float val = fmaf(acc[w], inv1, sh1);
    sz[tid * 33 + w] = fmaxf(val, 0.f);     // own row: no race
  }
  __syncthreads();
  for (int i = tid; i < TV; i += 256) y3[base + i] = __float2bfloat16(sz[i]);
}

// ---------------- K2: temporal conv (9 taps, dilation 33) + BN2 + res + ReLU
// grid (33, B), 256 thr. RESMODE: 0 = 1x1 res w/ fused input-BN (block0, fp32
// residual source), 1 = 1x1 res (block1, bf16 source), 2 = identity (block2).
template <int CO, int CIR, int RESMODE>
__global__ __launch_bounds__(256) void k2(const bf16* __restrict__ y3,
                                          const void* __restrict__ hres_,
                                          const float* __restrict__ ws,
                                          bf16* __restrict__ out,
                                          int wtO, int i2O, int b2O, int rwO, int rbO) {
  constexpr int CCH = 16;
  __shared__ float sy[CCH][520];            // 16 ch x (256 + 8*33 halo)
  const int tid = threadIdx.x;
  const int b = blockIdx.y;
  const int p0 = blockIdx.x * 256;
  const int p = p0 + tid;
  const float* wT = ws + wtO;
  float acc[CO];
#pragma unroll
  for (int o = 0; o < CO; o++) acc[o] = 0.f;

  for (int cc = 0; cc < CO / CCH; cc++) {
    __syncthreads();
    for (int i = tid; i < CCH * 520; i += 256) {
      int c = i / 520, off = i - c * 520;
      int q = p0 - 132 + off;               // flat plane index; OOB == T-edge zero pad
      float val = 0.f;
      if (q >= 0 && q < TV)
        val = cvt(y3[((size_t)(b * CO + cc * CCH + c)) * TV + q]);
      sy[c][off] = val;
    }
    __syncthreads();
    for (int c = 0; c < CCH; c++) {
      const float* wb = wT + ((cc * CCH + c) * 9) * CO;
#pragma unroll
      for (int k = 0; k < 9; k++) {
        float sv = sy[c][tid + k * 33];
        const float* w = wb + k * CO;       // thread-uniform -> s_load
#pragma unroll
        for (int o = 0; o < CO; o++) acc[o] = fmaf(w[o], sv, acc[o]);
      }
    }
  }

  // residual inputs
  float hv[RESMODE == 2 ? 1 : CIR];
  if constexpr (RESMODE == 0) {
    const float* hres = (const float*)hres_;
    const int v = p % 33;
#pragma unroll
    for (int ci = 0; ci < CIR; ci++) {
      float x = hres[((size_t)(b * CIR + ci)) * TV + p];
      hv[ci] = fmaf(x, ws[P_INV0 + ci * 33 + v], ws[P_BIAS0 + ci * 33 + v]);
    }
  } else if constexpr (RESMODE == 1) {
    const bf16* hres = (const bf16*)hres_;
#pragma unroll
    for (int ci = 0; ci < CIR; ci++)
      hv[ci] = cvt(hres[((size_t)(b * CIR + ci)) * TV + p]);
  }
  const float* i2 = ws + i2O;
  const float* b2 = ws + b2O;
#pragma unroll
  for (int o = 0; o < CO; o++) {
    float r;
    if constexpr (RESMODE == 2) {
      r = cvt(((const bf16*)hres_)[((size_t)(b * CO + o)) * TV + p]);
    } else {
      r = ws[rbO + o];
      const float* rw = ws + rwO + o * CIR;
#pragma unroll
      for (int ci = 0; ci < CIR; ci++) r = fmaf(rw[ci], hv[ci], r);
    }
    float val = fmaf(acc[o], i2[o], b2[o]) + r;
    out[((size_t)(b * CO + o)) * TV + p] = __float2bfloat16(fmaxf(val, 0.f));
  }
}

// ---------------- K3: global average pool over (T,V) ------------------------
__global__ __launch_bounds__(256) void k3(const bf16* __restrict__ h,
                                          float* __restrict__ feat) {
  const int n = blockIdx.x;                 // b*64 + o
  const int tid = threadIdx.x;
  const size_t base = (size_t)n * TV;
  float s = 0.f;
  for (int i = tid; i < TV; i += 256) s += cvt(h[base + i]);
#pragma unroll
  for (int off = 32; off > 0; off >>= 1) s += __shfl_down(s, off, 64);
  __shared__ float red[4];
  if ((tid & 63) == 0) red[tid >> 6] = s;
  __syncthreads();
  if (tid == 0) feat[n] = (red[0] + red[1] + red[2] + red[3]) * (1.f / (float)TV);
}

// ---------------- K4: final FC ----------------------------------------------
__global__ __launch_bounds__(128) void k4(const float* __restrict__ feat,
                                          const float* __restrict__ ws,
                                          float* __restrict__ out) {
  const int b = blockIdx.x;
  const int tid = threadIdx.x;
  __shared__ float sf[64];
  if (tid < 64) sf[tid] = feat[b * 64 + tid];
  __syncthreads();
  if (tid < 100) {
    const float* fw = ws + P_FCW + tid * 64;
    float a = ws[P_FCB + tid];
#pragma unroll
    for (int o = 0; o < 64; o++) a = fmaf(fw[o], sf[o], a);
    out[b * 100 + tid] = a;
  }
}

// ---------------- launch -----------------------------------------------------
extern "C" void kernel_launch(void* const* d_in, const int* in_sizes, int n_in,
                              void* d_out, int out_size, void* d_ws, size_t ws_size,
                              hipStream_t stream) {
  const float* xin = (const float*)d_in[0];
  float* wsf = (float*)d_ws;
  char* wsb = (char*)d_ws;
  bf16* buf0 = (bf16*)(wsb + PARAM_BYTES);
  bf16* buf1 = buf0 + BUF_ELEMS;
  bf16* buf2 = buf1 + BUF_ELEMS;
  float* outp = (float*)d_out;

  Ptrs ptrs;
  for (int i = 0; i < 48 && i < n_in; i++) ptrs.p[i] = (const float*)d_in[i];

  prep_kernel<<<7, 256, 0, stream>>>(ptrs, wsf);

  dim3 g33(33, NB);
  // block 0: 6 -> 32 (input BN fused into proj and residual reads)
  k1a_in<6, 32><<<g33, 256, 0, stream>>>(xin, wsf, buf0, P_PW0, P_PB0);
  k1b<<<NB * 32, 256, 0, stream>>>(buf0, wsf, buf1, P_I1_0, P_B1_0, 31);
  k2<32, 6, 0><<<g33, 256, 0, stream>>>(buf1, (const void*)xin, wsf, buf2, P_WT0, P_I2_0, P_B2_0, P_RW0, P_RB0);
  // block 1: 32 -> 64
  k1a<32, 64><<<g33, 256, 0, stream>>>(buf2, wsf, buf0, P_PW1, P_PB1);
  k1b<<<NB * 64, 256, 0, stream>>>(buf0, wsf, buf1, P_I1_1, P_B1_1, 63);
  k2<64, 32, 1><<<g33, 256, 0, stream>>>(buf1, (const void*)buf2, wsf, buf0, P_WT1, P_I2_1, P_B2_1, P_RW1, P_RB1);
  // block 2: 64 -> 64 (identity residual)
  k1a<64, 64><<<g33, 256, 0, stream>>>(buf0, wsf, buf1, P_PW2, P_PB2);
  k1b<<<NB * 64, 256, 0, stream>>>(buf1, wsf, buf2, P_I1_2, P_B1_2, 63);
  k2<64, 64, 2><<<g33, 256, 0, stream>>>(buf2, (const void*)buf0, wsf, buf1, P_WT2, P_I2_2, P_B2_2, 0, 0);
  // pool + fc
  k3<<<NB * 64, 256, 0, stream>>>(buf1, wsf + P_FEAT);
  k4<<<NB, 128, 0, stream>>>(wsf + P_FEAT, wsf, outp);
}

// Round 3
// 576.655 us; speedup vs baseline: 3.3869x; 3.3869x over previous
//
#include <hip/hip_runtime.h>

// ActionSTGCN on MI355X — round 3: MFMA restructure.
// Pixel-major bf16 activations [b][p][c] (p = t*33+v flat plane, c innermost).
// Temporal conv (9,1) == GEMM with K = (tap, c); tap shift = flat shift 33.
// Residual 1x1 convs folded into K (weights pre-scaled by 1/i2 so epilogue
// BN2 scale applies only to the conv part). k1a (1x1 proj) = same GEMM with
// TAPS=1. k1b (adjacency mix) stays VALU, in-place.

typedef short bf16s;  // bf16 bit pattern
using v8s = __attribute__((ext_vector_type(8))) short;
using v4f = __attribute__((ext_vector_type(4))) float;

#define TV 8448
#define NB 64
#define EPSBN 1e-5f

__device__ __forceinline__ float b2f(short s) {
  unsigned u = ((unsigned)(unsigned short)s) << 16;
  return __builtin_bit_cast(float, u);
}
__device__ __forceinline__ short f2b(float f) {
  unsigned u = __builtin_bit_cast(unsigned, f);
  u += 0x7FFFu + ((u >> 16) & 1u);   // RNE
  return (short)(u >> 16);
}

// ---------------- fp32 param offsets (words) --------------------------------
constexpr int P_A     = 0;        // 1089 adjacency
constexpr int P_INV0  = 1089;     // 198 input-BN scale (c*33+v)
constexpr int P_BIAS0 = 1287;     // 198
constexpr int P_PW0T  = 1485;     // 192 proj0 W [c*32+o]
constexpr int P_PB0   = 1677;     // 32
constexpr int P_I1_0  = 1709;  constexpr int P_B1_0 = 1741;
constexpr int P_I2_0  = 1773;  constexpr int P_B2_0 = 1805;
constexpr int P_I1_1  = 1837;  constexpr int P_B1_1 = 1901;
constexpr int P_I2_1  = 1965;  constexpr int P_B2_1 = 2029;
constexpr int P_I1_2  = 2093;  constexpr int P_B1_2 = 2157;
constexpr int P_I2_2  = 2221;  constexpr int P_B2_2 = 2285;
constexpr int P_PB1   = 2349;     // 64 proj1 bias
constexpr int P_PB2   = 2413;     // 64
constexpr int P_FCW   = 2477;     // 6400
constexpr int P_FCB   = 8877;     // 100
constexpr int P_PART  = 8977;     // 64*8*64 pool partials
// end = 41745 words -> 166980 B
constexpr size_t FRAG_OFF = 167168;            // 256-aligned
// bf16 fragment arrays (element offsets within frag region)
constexpr int FK2_0  = 0;      // 10 steps * NT2 * 512 = 10240
constexpr int FK2_1  = 10240;  // 19 * 4 * 512 = 38912
constexpr int FK2_2  = 49152;  // 20 * 4 * 512 = 40960
constexpr int FK1A1  = 90112;  // 1 * 4 * 512 = 2048
constexpr int FK1A2  = 92160;  // 2 * 4 * 512 = 4096
constexpr size_t FRAG_BYTES = 96256 * 2;       // 192512
constexpr size_t PARAM_BYTES = FRAG_OFF + FRAG_BYTES;   // 359680 (256-aligned)
constexpr size_t BUF_ELEMS = (size_t)NB * TV * 64;      // 34,603,008 bf16

// ---------------- prep ------------------------------------------------------
struct Ptrs { const float* p[48]; };

__device__ void bn1set(int tid, float* inv, float* sh, const float* g,
                       const float* b, const float* m, const float* v, int n) {
  for (int i = tid; i < n; i += 256) {
    float iv = g[i] / sqrtf(v[i] + EPSBN);
    inv[i] = iv; sh[i] = b[i] - m[i] * iv;
  }
}
__device__ void bn2set(int tid, float* inv, float* sh, const float* tb,
                       const float* g, const float* b, const float* m,
                       const float* v, const float* rb, int n) {
  for (int i = tid; i < n; i += 256) {
    float iv = g[i] / sqrtf(v[i] + EPSBN);
    inv[i] = iv;
    sh[i] = tb[i] * iv + b[i] - m[i] * iv + (rb ? rb[i] : 0.f);
  }
}

// B-fragment maker for k2-style GEMM. Layout: elem((s*NT+nt)*512 + lane*8 + j)
// = B[kk = (lane>>4)*8+j][o = nt*16 + (lane&15)] for K-step s.
__device__ void make_k2_frags(int tid, short* dst, const float* tw, const float* rw,
                              const float* g2, const float* v2,
                              int CI, int NT, int TAPS, int CIR, int ident,
                              int nsteps) {
  const int conv = (CI / 32) * TAPS;
  const int total = nsteps * NT * 512;
  for (int idx = tid; idx < total; idx += 256) {
    int s = idx / (NT * 512), r = idx % (NT * 512);
    int nt = r / 512, r2 = r % 512;
    int lane = r2 >> 3, j = r2 & 7;
    int o = nt * 16 + (lane & 15);
    int kk = ((lane >> 4) * 8) + j;
    float val = 0.f;
    if (s < conv) {
      int cc = s / TAPS, tap = s % TAPS;
      int c = cc * 32 + kk;
      val = tw[(o * CI + c) * 9 + tap];
    } else {
      int ci = (s - conv) * 32 + kk;
      float i2 = g2[o] / sqrtf(v2[o] + EPSBN);
      if (ident) { if (ci == o) val = 1.f / i2; }
      else if (ci < CIR) val = rw[o * CIR + ci] / i2;
    }
    dst[idx] = f2b(val);
  }
}

__device__ void make_k1a_frags(int tid, short* dst, const float* pw, int CI) {
  const int nsteps = CI / 32, NT = 4;
  const int total = nsteps * NT * 512;
  for (int idx = tid; idx < total; idx += 256) {
    int s = idx / (NT * 512), r = idx % (NT * 512);
    int nt = r / 512, r2 = r % 512;
    int lane = r2 >> 3, j = r2 & 7;
    int o = nt * 16 + (lane & 15);
    int c = s * 32 + ((lane >> 4) * 8) + j;
    dst[idx] = f2b(pw[o * CI + c]);
  }
}

__global__ __launch_bounds__(256) void prep_kernel(Ptrs in, float* __restrict__ ws,
                                                   short* __restrict__ fr) {
  const int tid = threadIdx.x;
  switch (blockIdx.x) {
    case 0: {
      for (int i = tid; i < 1089; i += 256) ws[P_A + i] = in.p[1][i];
      for (int i = tid; i < 198; i += 256) {
        float iv = in.p[2][i] / sqrtf(in.p[5][i] + EPSBN);
        ws[P_INV0 + i] = iv; ws[P_BIAS0 + i] = in.p[3][i] - in.p[4][i] * iv;
      }
      for (int i = tid; i < 192; i += 256) {
        int c = i >> 5, o = i & 31;
        ws[P_PW0T + i] = in.p[6][o * 6 + c];
      }
      for (int i = tid; i < 32; i += 256) ws[P_PB0 + i] = in.p[7][i];
      for (int i = tid; i < 64; i += 256) { ws[P_PB1 + i] = in.p[21][i]; ws[P_PB2 + i] = in.p[35][i]; }
      bn1set(tid, ws + P_I1_0, ws + P_B1_0, in.p[8],  in.p[9],  in.p[10], in.p[11], 32);
      bn1set(tid, ws + P_I1_1, ws + P_B1_1, in.p[22], in.p[23], in.p[24], in.p[25], 64);
      bn1set(tid, ws + P_I1_2, ws + P_B1_2, in.p[36], in.p[37], in.p[38], in.p[39], 64);
      bn2set(tid, ws + P_I2_0, ws + P_B2_0, in.p[13], in.p[14], in.p[15], in.p[16], in.p[17], in.p[19], 32);
      bn2set(tid, ws + P_I2_1, ws + P_B2_1, in.p[27], in.p[28], in.p[29], in.p[30], in.p[31], in.p[33], 64);
      bn2set(tid, ws + P_I2_2, ws + P_B2_2, in.p[41], in.p[42], in.p[43], in.p[44], in.p[45], nullptr, 64);
      for (int i = tid; i < 6400; i += 256) ws[P_FCW + i] = in.p[46][i];
      for (int i = tid; i < 100; i += 256) ws[P_FCB + i] = in.p[47][i];
      break;
    }
    case 1: make_k2_frags(tid, fr + FK2_0, in.p[12], in.p[18], in.p[14], in.p[17], 32, 2, 9, 6, 0, 10); break;
    case 2: make_k2_frags(tid, fr + FK2_1, in.p[26], in.p[32], in.p[28], in.p[31], 64, 4, 9, 32, 0, 19); break;
    case 3: make_k2_frags(tid, fr + FK2_2, in.p[40], nullptr,  in.p[42], in.p[45], 64, 4, 9, 0, 1, 20); break;
    case 4: make_k1a_frags(tid, fr + FK1A1, in.p[20], 32); break;
    case 5: make_k1a_frags(tid, fr + FK1A2, in.p[34], 64); break;
  }
}

// ---------------- k0: input BN + proj0 (6->32) + xb emit --------------------
__global__ __launch_bounds__(256) void k0_kern(const float* __restrict__ x,
                                               const float* __restrict__ ws,
                                               short* __restrict__ z0,
                                               short* __restrict__ xb) {
  const int tid = threadIdx.x;
  const int p = blockIdx.x * 256 + tid, b = blockIdx.y;
  const int v = p % 33;
  float hv[6];
#pragma unroll
  for (int c = 0; c < 6; c++) {
    float xv = x[((size_t)(b * 6 + c)) * TV + p];
    hv[c] = fmaf(xv, ws[P_INV0 + c * 33 + v], ws[P_BIAS0 + c * 33 + v]);
  }
  v8s xv8;
#pragma unroll
  for (int c = 0; c < 6; c++) xv8[c] = f2b(hv[c]);
  xv8[6] = 0; xv8[7] = 0;
  *(v8s*)(xb + ((size_t)b * TV + p) * 8) = xv8;
  float acc[32];
#pragma unroll
  for (int o = 0; o < 32; o++) acc[o] = ws[P_PB0 + o];
#pragma unroll
  for (int c = 0; c < 6; c++)
#pragma unroll
    for (int o = 0; o < 32; o++) acc[o] = fmaf(hv[c], ws[P_PW0T + c * 32 + o], acc[o]);
  v8s* dst = (v8s*)(z0 + ((size_t)b * TV + p) * 32);
#pragma unroll
  for (int u = 0; u < 4; u++) {
    v8s t;
#pragma unroll
    for (int j = 0; j < 8; j++) t[j] = f2b(acc[u * 8 + j]);
    dst[u] = t;
  }
}

// ---------------- k1b: adjacency mix + BN1 + ReLU, in place -----------------
// block = (tg of 8 t's, b). Stage 264xCO rows in LDS, compute, write back.
template <int CO>
__global__ __launch_bounds__(256) void k1b_kern(short* __restrict__ z,
                                                const float* __restrict__ ws,
                                                int i1O, int b1O) {
  __shared__ __align__(16) short sz[264 * CO];
  const int tid = threadIdx.x;
  const int tg = blockIdx.x, b = blockIdx.y;
  short* base = z + ((size_t)b * TV + tg * 264) * CO;
  constexpr int UNITS = 264 * CO / 8;
  for (int u = tid; u < UNITS; u += 256)
    *(v8s*)(sz + u * 8) = *(const v8s*)(base + u * 8);
  __syncthreads();
  const int tl = tid >> 5, oc = tid & 31;
  float a0[33], a1[(CO == 64) ? 33 : 1];
#pragma unroll
  for (int w = 0; w < 33; w++) a0[w] = 0.f;
  if constexpr (CO == 64) {
#pragma unroll
    for (int w = 0; w < 33; w++) a1[w] = 0.f;
  }
  for (int v = 0; v < 33; v++) {
    float z0v = b2f(sz[(tl * 33 + v) * CO + oc]);
    float z1v = (CO == 64) ? b2f(sz[(tl * 33 + v) * CO + oc + 32]) : 0.f;
#pragma unroll
    for (int w = 0; w < 33; w++) {
      float Av = ws[P_A + v * 33 + w];
      a0[w] = fmaf(Av, z0v, a0[w]);
      if constexpr (CO == 64) a1[w] = fmaf(Av, z1v, a1[w]);
    }
  }
  const float i10 = ws[i1O + oc], s10 = ws[b1O + oc];
  float i11 = 0.f, s11 = 0.f;
  if constexpr (CO == 64) { i11 = ws[i1O + oc + 32]; s11 = ws[b1O + oc + 32]; }
  __syncthreads();
#pragma unroll
  for (int w = 0; w < 33; w++) {
    sz[(tl * 33 + w) * CO + oc] = f2b(fmaxf(fmaf(a0[w], i10, s10), 0.f));
    if constexpr (CO == 64)
      sz[(tl * 33 + w) * CO + oc + 32] = f2b(fmaxf(fmaf(a1[w], i11, s11), 0.f));
  }
  __syncthreads();
  for (int u = tid; u < UNITS; u += 256)
    *(v8s*)(base + u * 8) = *(const v8s*)(sz + u * 8);
}

// ---------------- gemm: MFMA conv/proj kernel -------------------------------
// Block = 256 px x CO. 4 waves, wave owns 4 m-tiles(16px) x all NT n-tiles.
// K = taps x channels (32-ch chunks) + folded residual chunks.
template <int CI, int CO, int TAPS, int RSTRIDE, bool K2EPI>
__global__ __launch_bounds__(256, 2) void gemm_kern(
    const short* __restrict__ act, const short* __restrict__ res,
    const short* __restrict__ wfrag, const float* __restrict__ ws,
    short* __restrict__ out, int sAO, int sBO) {
  constexpr int NT = CO / 16;
  constexpr int H = (TAPS - 1) / 2 * 33;
  constexpr int WIN = 256 + 2 * H;
  constexpr int RS = 40;                 // LDS row stride (bf16): 80B, 16B-aligned
  constexpr int NCH = CI / 32;
  constexpr int RCH = (RSTRIDE == 0) ? 0 : ((RSTRIDE == 64) ? 2 : 1);
  __shared__ __align__(16) short sw[WIN * RS];
  const int tid = threadIdx.x;
  const int b = blockIdx.y;
  const int p0 = blockIdx.x * 256;
  const int lane = tid & 63, wv = tid >> 6;
  const int ln = lane & 15, q8 = (lane >> 4) * 8;
  const int wvbase = wv * 64;
  const v8s* wf = (const v8s*)wfrag;
  v4f acc[4][NT];
#pragma unroll
  for (int mt = 0; mt < 4; mt++)
#pragma unroll
    for (int nt = 0; nt < NT; nt++) acc[mt][nt] = (v4f){0.f, 0.f, 0.f, 0.f};

  auto do_step = [&](int tapOff, int s) {
    v8s afr[4];
#pragma unroll
    for (int mt = 0; mt < 4; mt++)
      afr[mt] = *(const v8s*)(sw + (wvbase + mt * 16 + ln + tapOff) * RS + q8);
    v8s bfr[NT];
#pragma unroll
    for (int nt = 0; nt < NT; nt++) bfr[nt] = wf[(s * NT + nt) * 64 + lane];
#pragma unroll
    for (int mt = 0; mt < 4; mt++)
#pragma unroll
      for (int nt = 0; nt < NT; nt++)
        acc[mt][nt] = __builtin_amdgcn_mfma_f32_16x16x32_bf16(
            afr[mt], bfr[nt], acc[mt][nt], 0, 0, 0);
  };

  int s = 0;
  for (int cc = 0; cc < NCH; cc++) {
    __syncthreads();
    const short* src = act + (size_t)b * TV * CI + cc * 32;
    for (int u = tid; u < WIN * 4; u += 256) {
      int off = u >> 2, c0 = (u & 3) * 8;
      int qp = p0 - H + off;
      v8s val = {0, 0, 0, 0, 0, 0, 0, 0};
      if (qp >= 0 && qp < TV) val = *(const v8s*)(src + (size_t)qp * CI + c0);
      *(v8s*)(sw + off * RS + c0) = val;
    }
    __syncthreads();
    for (int tap = 0; tap < TAPS; tap++, s++) do_step(tap * 33, s);
  }
  if constexpr (RSTRIDE > 0) {
    for (int rc = 0; rc < RCH; rc++, s++) {
      __syncthreads();
      const short* rsrc = res + (size_t)b * TV * RSTRIDE;
      if constexpr (RSTRIDE == 8) {
        int off = tid;
        v8s val = *(const v8s*)(rsrc + (size_t)(p0 + off) * 8);
        v8s zz = {0, 0, 0, 0, 0, 0, 0, 0};
        *(v8s*)(sw + off * RS + 0) = val;
        *(v8s*)(sw + off * RS + 8) = zz;
        *(v8s*)(sw + off * RS + 16) = zz;
        *(v8s*)(sw + off * RS + 24) = zz;
      } else {
        const short* src = rsrc + rc * 32;
        for (int u = tid; u < 256 * 4; u += 256) {
          int off = u >> 2, c0 = (u & 3) * 8;
          v8s val = *(const v8s*)(src + (size_t)(p0 + off) * RSTRIDE + c0);
          *(v8s*)(sw + off * RS + c0) = val;
        }
      }
      __syncthreads();
      do_step(0, s);
    }
  }
  // epilogue: D row = (lane>>4)*4 + r, col = lane&15  [m89/m91-verified layout]
#pragma unroll
  for (int nt = 0; nt < NT; nt++) {
    int o = nt * 16 + ln;
    float sA = ws[sAO + o];
    float sB = K2EPI ? ws[sBO + o] : 0.f;
#pragma unroll
    for (int mt = 0; mt < 4; mt++)
#pragma unroll
      for (int r = 0; r < 4; r++) {
        int pm = wvbase + mt * 16 + (lane >> 4) * 4 + r;
        float va = acc[mt][nt][r];
        float val = K2EPI ? fmaxf(fmaf(va, sA, sB), 0.f) : (va + sA);
        out[((size_t)b * TV + p0 + pm) * CO + o] = f2b(val);
      }
  }
}

// ---------------- k3: pool partials over (T,V) ------------------------------
__global__ __launch_bounds__(256) void k3_kern(const short* __restrict__ h,
                                               float* __restrict__ ws) {
  const int tid = threadIdx.x;
  const int pg = blockIdx.x, b = blockIdx.y;
  const int c = tid & 63, sub = tid >> 6;
  const short* hb = h + (size_t)b * TV * 64;
  float s = 0.f;
  for (int i = 0; i < 264; i++) {
    int p = pg * 1056 + i * 4 + sub;
    s += b2f(hb[(size_t)p * 64 + c]);
  }
  __shared__ float red[4][64];
  red[sub][c] = s;
  __syncthreads();
  if (sub == 0)
    ws[P_PART + ((size_t)b * 8 + pg) * 64 + c] =
        red[0][c] + red[1][c] + red[2][c] + red[3][c];
}

// ---------------- k4: FC ----------------------------------------------------
__global__ __launch_bounds__(128) void k4_kern(const float* __restrict__ ws,
                                               float* __restrict__ out) {
  const int b = blockIdx.x, tid = threadIdx.x;
  __shared__ float sf[64];
  if (tid < 64) {
    float s = 0.f;
#pragma unroll
    for (int pg = 0; pg < 8; pg++) s += ws[P_PART + ((size_t)b * 8 + pg) * 64 + tid];
    sf[tid] = s * (1.f / 8448.f);
  }
  __syncthreads();
  if (tid < 100) {
    float a = ws[P_FCB + tid];
#pragma unroll
    for (int o = 0; o < 64; o++) a = fmaf(ws[P_FCW + tid * 64 + o], sf[o], a);
    out[b * 100 + tid] = a;
  }
}

// ---------------- launch -----------------------------------------------------
extern "C" void kernel_launch(void* const* d_in, const int* in_sizes, int n_in,
                              void* d_out, int out_size, void* d_ws, size_t ws_size,
                              hipStream_t stream) {
  const float* xin = (const float*)d_in[0];
  float* wsf = (float*)d_ws;
  char* wsb = (char*)d_ws;
  short* frags = (short*)(wsb + FRAG_OFF);
  short* W0 = (short*)(wsb + PARAM_BYTES);
  short* W1 = W0 + BUF_ELEMS;
  short* W2 = W1 + BUF_ELEMS;
  short* xb = W2;  // alive k0 -> k2_0; W2 first written (as h1) at k2_1

  Ptrs ptrs;
  for (int i = 0; i < 48 && i < n_in; i++) ptrs.p[i] = (const float*)d_in[i];

  prep_kernel<<<6, 256, 0, stream>>>(ptrs, wsf, frags);

  dim3 g33(33, NB), g32(32, NB);
  // block 0: x -> BN -> proj(6->32) [k0], A-mix [k1b], tcn+res [gemm]
  k0_kern<<<g33, 256, 0, stream>>>(xin, wsf, W0, xb);
  k1b_kern<32><<<g32, 256, 0, stream>>>(W0, wsf, P_I1_0, P_B1_0);
  gemm_kern<32, 32, 9, 8, true><<<g33, 256, 0, stream>>>(
      W0, xb, frags + FK2_0, wsf, W1, P_I2_0, P_B2_0);            // -> h0 (W1)
  // block 1
  gemm_kern<32, 64, 1, 0, false><<<g33, 256, 0, stream>>>(
      W1, nullptr, frags + FK1A1, wsf, W0, P_PB1, 0);             // proj -> z1 (W0)
  k1b_kern<64><<<g32, 256, 0, stream>>>(W0, wsf, P_I1_1, P_B1_1);
  gemm_kern<64, 64, 9, 32, true><<<g33, 256, 0, stream>>>(
      W0, W1, frags + FK2_1, wsf, W2, P_I2_1, P_B2_1);            // -> h1 (W2)
  // block 2
  gemm_kern<64, 64, 1, 0, false><<<g33, 256, 0, stream>>>(
      W2, nullptr, frags + FK1A2, wsf, W0, P_PB2, 0);             // proj -> z2 (W0)
  k1b_kern<64><<<g32, 256, 0, stream>>>(W0, wsf, P_I1_2, P_B1_2);
  gemm_kern<64, 64, 9, 64, true><<<g33, 256, 0, stream>>>(
      W0, W2, frags + FK2_2, wsf, W1, P_I2_2, P_B2_2);            // -> h2 (W1)
  // pool + fc
  k3_kern<<<dim3(8, NB), 256, 0, stream>>>(W1, wsf);
  k4_kern<<<NB, 128, 0, stream>>>(wsf, (float*)d_out);
}

// Round 4
// 540.308 us; speedup vs baseline: 3.6147x; 1.0673x over previous
//
#include <hip/hip_runtime.h>

// ActionSTGCN on MI355X — round 4: fusion + prefetch.
// Pipeline: pm0 (BNin+proj0+Amix+bn1relu) -> tcn0 -> pm1 (proj+mix) -> tcn1
//           -> pm2 -> tcn2 (+fused global-avg-pool) -> k4 (FC).
// Activations bf16 pixel-major [b][p][c], p = t*33+v flat plane; temporal conv
// = GEMM with K=(tap,chan), tap shift = flat shift 33; residual 1x1 folded
// into K-steps (weights pre-scaled 1/i2).

typedef short bf16s;
using v8s = __attribute__((ext_vector_type(8))) short;
using v4f = __attribute__((ext_vector_type(4))) float;

#define TV 8448
#define NB 64
#define EPSBN 1e-5f

__device__ __forceinline__ float b2f(short s) {
  unsigned u = ((unsigned)(unsigned short)s) << 16;
  return __builtin_bit_cast(float, u);
}
__device__ __forceinline__ short f2b(float f) {
  unsigned u = __builtin_bit_cast(unsigned, f);
  u += 0x7FFFu + ((u >> 16) & 1u);   // RNE
  return (short)(u >> 16);
}

// ---------------- fp32 param offsets (words) --------------------------------
constexpr int P_A     = 0;        // 1089 adjacency
constexpr int P_INV0  = 1089;     // 198 input-BN scale (c*33+v)
constexpr int P_BIAS0 = 1287;     // 198
constexpr int P_PW0T  = 1485;     // 192 proj0 W [c*32+o]
constexpr int P_PB0   = 1677;     // 32
constexpr int P_I1_0  = 1709;  constexpr int P_B1_0 = 1741;
constexpr int P_I2_0  = 1773;  constexpr int P_B2_0 = 1805;
constexpr int P_I1_1  = 1837;  constexpr int P_B1_1 = 1901;
constexpr int P_I2_1  = 1965;  constexpr int P_B2_1 = 2029;
constexpr int P_I1_2  = 2093;  constexpr int P_B1_2 = 2157;
constexpr int P_I2_2  = 2221;  constexpr int P_B2_2 = 2285;
constexpr int P_PB1   = 2349;     // 64
constexpr int P_PB2   = 2413;     // 64
constexpr int P_FCW   = 2477;     // 6400
constexpr int P_FCB   = 8877;     // 100
constexpr int P_FEAT  = 8977;     // 64*64 pooled sums (fp32, atomicAdd)
// end 13073 words
constexpr size_t FRAG_OFF = 167168;
constexpr int FK2_0  = 0;      // 10 steps * 2nt * 512
constexpr int FK2_1  = 10240;  // 19 * 4 * 512
constexpr int FK2_2  = 49152;  // 20 * 4 * 512
constexpr int FK1A1  = 90112;  // 1 * 4 * 512
constexpr int FK1A2  = 92160;  // 2 * 4 * 512
constexpr size_t FRAG_BYTES = 96256 * 2;
constexpr size_t PARAM_BYTES = FRAG_OFF + FRAG_BYTES;
constexpr size_t HBUF = (size_t)NB * TV * 64;   // 34,603,008 elems per region

// ---------------- prep ------------------------------------------------------
struct Ptrs { const float* p[48]; };

__device__ void bn1set(int tid, float* inv, float* sh, const float* g,
                       const float* b, const float* m, const float* v, int n) {
  for (int i = tid; i < n; i += 256) {
    float iv = g[i] / sqrtf(v[i] + EPSBN);
    inv[i] = iv; sh[i] = b[i] - m[i] * iv;
  }
}
__device__ void bn2set(int tid, float* inv, float* sh, const float* tb,
                       const float* g, const float* b, const float* m,
                       const float* v, const float* rb, int n) {
  for (int i = tid; i < n; i += 256) {
    float iv = g[i] / sqrtf(v[i] + EPSBN);
    inv[i] = iv;
    sh[i] = tb[i] * iv + b[i] - m[i] * iv + (rb ? rb[i] : 0.f);
  }
}

// B-fragment layout: elem((s*NT+nt)*512 + lane*8 + j) = B[kk=(lane>>4)*8+j][o=nt*16+(lane&15)]
__device__ void make_k2_frags(int tid, short* dst, const float* tw, const float* rw,
                              const float* g2, const float* v2,
                              int CI, int NT, int TAPS, int CIR, int ident,
                              int nsteps) {
  const int conv = (CI / 32) * TAPS;
  const int total = nsteps * NT * 512;
  for (int idx = tid; idx < total; idx += 256) {
    int s = idx / (NT * 512), r = idx % (NT * 512);
    int nt = r / 512, r2 = r % 512;
    int lane = r2 >> 3, j = r2 & 7;
    int o = nt * 16 + (lane & 15);
    int kk = ((lane >> 4) * 8) + j;
    float val = 0.f;
    if (s < conv) {
      int cc = s / TAPS, tap = s % TAPS;
      int c = cc * 32 + kk;
      val = tw[(o * CI + c) * 9 + tap];
    } else {
      int ci = (s - conv) * 32 + kk;
      float i2 = g2[o] / sqrtf(v2[o] + EPSBN);
      if (ident) { if (ci == o) val = 1.f / i2; }
      else if (ci < CIR) val = rw[o * CIR + ci] / i2;
    }
    dst[idx] = f2b(val);
  }
}

__device__ void make_k1a_frags(int tid, short* dst, const float* pw, int CI) {
  const int nsteps = CI / 32, NT = 4;
  const int total = nsteps * NT * 512;
  for (int idx = tid; idx < total; idx += 256) {
    int s = idx / (NT * 512), r = idx % (NT * 512);
    int nt = r / 512, r2 = r % 512;
    int lane = r2 >> 3, j = r2 & 7;
    int o = nt * 16 + (lane & 15);
    int c = s * 32 + ((lane >> 4) * 8) + j;
    dst[idx] = f2b(pw[o * CI + c]);
  }
}

__global__ __launch_bounds__(256) void prep_kernel(Ptrs in, float* __restrict__ ws,
                                                   short* __restrict__ fr) {
  const int tid = threadIdx.x;
  switch (blockIdx.x) {
    case 0: {
      for (int i = tid; i < 1089; i += 256) ws[P_A + i] = in.p[1][i];
      for (int i = tid; i < 198; i += 256) {
        float iv = in.p[2][i] / sqrtf(in.p[5][i] + EPSBN);
        ws[P_INV0 + i] = iv; ws[P_BIAS0 + i] = in.p[3][i] - in.p[4][i] * iv;
      }
      for (int i = tid; i < 192; i += 256) {
        int c = i >> 5, o = i & 31;
        ws[P_PW0T + i] = in.p[6][o * 6 + c];
      }
      for (int i = tid; i < 32; i += 256) ws[P_PB0 + i] = in.p[7][i];
      for (int i = tid; i < 64; i += 256) { ws[P_PB1 + i] = in.p[21][i]; ws[P_PB2 + i] = in.p[35][i]; }
      bn1set(tid, ws + P_I1_0, ws + P_B1_0, in.p[8],  in.p[9],  in.p[10], in.p[11], 32);
      bn1set(tid, ws + P_I1_1, ws + P_B1_1, in.p[22], in.p[23], in.p[24], in.p[25], 64);
      bn1set(tid, ws + P_I1_2, ws + P_B1_2, in.p[36], in.p[37], in.p[38], in.p[39], 64);
      bn2set(tid, ws + P_I2_0, ws + P_B2_0, in.p[13], in.p[14], in.p[15], in.p[16], in.p[17], in.p[19], 32);
      bn2set(tid, ws + P_I2_1, ws + P_B2_1, in.p[27], in.p[28], in.p[29], in.p[30], in.p[31], in.p[33], 64);
      bn2set(tid, ws + P_I2_2, ws + P_B2_2, in.p[41], in.p[42], in.p[43], in.p[44], in.p[45], nullptr, 64);
      for (int i = tid; i < 6400; i += 256) ws[P_FCW + i] = in.p[46][i];
      for (int i = tid; i < 100; i += 256) ws[P_FCB + i] = in.p[47][i];
      for (int i = tid; i < 4096; i += 256) ws[P_FEAT + i] = 0.f;   // pool accum
      break;
    }
    case 1: make_k2_frags(tid, fr + FK2_0, in.p[12], in.p[18], in.p[14], in.p[17], 32, 2, 9, 6, 0, 10); break;
    case 2: make_k2_frags(tid, fr + FK2_1, in.p[26], in.p[32], in.p[28], in.p[31], 64, 4, 9, 32, 0, 19); break;
    case 3: make_k2_frags(tid, fr + FK2_2, in.p[40], nullptr,  in.p[42], in.p[45], 64, 4, 9, 0, 1, 20); break;
    case 4: make_k1a_frags(tid, fr + FK1A1, in.p[20], 32); break;
    case 5: make_k1a_frags(tid, fr + FK1A2, in.p[34], 64); break;
  }
}

// ---------------- pm0: input BN + proj0 (6->32, VALU) + A-mix + bn1relu -----
// block = (tg of 8 t's = 264 rows, b). Also emits xb (8-ch packed BN'd x).
__global__ __launch_bounds__(256) void pm0_kern(const float* __restrict__ x,
                                                const float* __restrict__ ws,
                                                short* __restrict__ y0,
                                                short* __restrict__ xb) {
  __shared__ __align__(16) short zb[264 * 32];
  const int tid = threadIdx.x;
  const int tg = blockIdx.x, b = blockIdx.y;
  const int rows0 = tg * 264;
  for (int i = tid; i < 264; i += 256) {
    int p = rows0 + i;
    int v = i % 33;
    float hv[6];
#pragma unroll
    for (int c = 0; c < 6; c++) {
      float xv = x[((size_t)(b * 6 + c)) * TV + p];
      hv[c] = fmaf(xv, ws[P_INV0 + c * 33 + v], ws[P_BIAS0 + c * 33 + v]);
    }
    v8s xv8;
#pragma unroll
    for (int c = 0; c < 6; c++) xv8[c] = f2b(hv[c]);
    xv8[6] = 0; xv8[7] = 0;
    *(v8s*)(xb + ((size_t)b * TV + p) * 8) = xv8;
    float acc[32];
#pragma unroll
    for (int o = 0; o < 32; o++) acc[o] = ws[P_PB0 + o];
#pragma unroll
    for (int c = 0; c < 6; c++)
#pragma unroll
      for (int o = 0; o < 32; o++) acc[o] = fmaf(hv[c], ws[P_PW0T + c * 32 + o], acc[o]);
#pragma unroll
    for (int o = 0; o < 32; o++) zb[i * 32 + o] = f2b(acc[o]);
  }
  __syncthreads();
  // A-mix + bn1 + relu in place (each thread owns slots (tl, :, oc))
  const int tl = tid >> 5, oc = tid & 31;
  float a0[33];
#pragma unroll
  for (int w = 0; w < 33; w++) a0[w] = 0.f;
  for (int v = 0; v < 33; v++) {
    float z0 = b2f(zb[(tl * 33 + v) * 32 + oc]);
#pragma unroll
    for (int w = 0; w < 33; w++) a0[w] = fmaf(ws[P_A + v * 33 + w], z0, a0[w]);
  }
  const float i10 = ws[P_I1_0 + oc], s10 = ws[P_B1_0 + oc];
#pragma unroll
  for (int w = 0; w < 33; w++)
    zb[(tl * 33 + w) * 32 + oc] = f2b(fmaxf(fmaf(a0[w], i10, s10), 0.f));
  __syncthreads();
  short* dst = y0 + ((size_t)b * TV + rows0) * 32;
  for (int u = tid; u < 264 * 4; u += 256)
    *(v8s*)(dst + u * 8) = *(const v8s*)(zb + u * 8);
}

// ---------------- pm: MFMA proj (CI->64) + A-mix + bn1relu ------------------
// block = (tg of 8 t's, b). Stages 272 rows (8 pad), 17 m-tiles (wave0 gets 5).
template <int CI>
__global__ __launch_bounds__(256, 2) void pm_kern(const short* __restrict__ in,
                                                  const short* __restrict__ wfrag,
                                                  const float* __restrict__ ws,
                                                  short* __restrict__ y,
                                                  int pbO, int i1O, int b1O) {
  constexpr int KS = CI / 32;
  constexpr int RSI = (CI == 64) ? 72 : 40;   // 16B-aligned row strides
  constexpr int CIV = CI / 8;
  __shared__ __align__(16) short swi[272 * RSI];
  __shared__ __align__(16) short zb[272 * 64];
  const int tid = threadIdx.x;
  const int tg = blockIdx.x, b = blockIdx.y;
  const int rows0 = tg * 264;
  const int lane = tid & 63, wv = tid >> 6;
  const int ln = lane & 15, q8 = (lane >> 4) * 8;

  const short* src = in + (size_t)b * TV * CI;
  for (int u = tid; u < 272 * CIV; u += 256) {
    int off = u / CIV, c0 = (u % CIV) * 8;
    int qp = rows0 + off;
    v8s val = {0, 0, 0, 0, 0, 0, 0, 0};
    if (qp < TV) val = *(const v8s*)(src + (size_t)qp * CI + c0);
    *(v8s*)(swi + off * RSI + c0) = val;
  }
  const v8s* wf = (const v8s*)wfrag;
  v8s bf[KS][4];
#pragma unroll
  for (int ks = 0; ks < KS; ks++)
#pragma unroll
    for (int nt = 0; nt < 4; nt++) bf[ks][nt] = wf[(ks * 4 + nt) * 64 + lane];
  __syncthreads();

  v4f acc[5][4];
#pragma unroll
  for (int i = 0; i < 5; i++)
#pragma unroll
    for (int nt = 0; nt < 4; nt++) acc[i][nt] = (v4f){0.f, 0.f, 0.f, 0.f};
#pragma unroll
  for (int i = 0; i < 5; i++) {
    if (i < 4 || wv == 0) {
      int tile = wv + 4 * i;
#pragma unroll
      for (int ks = 0; ks < KS; ks++) {
        v8s afr = *(const v8s*)(swi + (tile * 16 + ln) * RSI + ks * 32 + q8);
#pragma unroll
        for (int nt = 0; nt < 4; nt++)
          acc[i][nt] = __builtin_amdgcn_mfma_f32_16x16x32_bf16(afr, bf[ks][nt], acc[i][nt], 0, 0, 0);
      }
    }
  }
  // z -> LDS (C-layout: row = tile*16 + quad*4 + r, col = lane&15 + nt*16)
#pragma unroll
  for (int i = 0; i < 5; i++) {
    if (i < 4 || wv == 0) {
      int tile = wv + 4 * i;
#pragma unroll
      for (int nt = 0; nt < 4; nt++) {
        int o = nt * 16 + ln;
        float pb = ws[pbO + o];
#pragma unroll
        for (int r = 0; r < 4; r++) {
          int pm = tile * 16 + (lane >> 4) * 4 + r;
          zb[pm * 64 + o] = f2b(acc[i][nt][r] + pb);
        }
      }
    }
  }
  __syncthreads();
  // A-mix + bn1 + relu in place, both channel halves per thread
  const int tl = tid >> 5, oc = tid & 31;
  float a0[33], a1[33];
#pragma unroll
  for (int w = 0; w < 33; w++) { a0[w] = 0.f; a1[w] = 0.f; }
  for (int v = 0; v < 33; v++) {
    float z0 = b2f(zb[(tl * 33 + v) * 64 + oc]);
    float z1 = b2f(zb[(tl * 33 + v) * 64 + oc + 32]);
#pragma unroll
    for (int w = 0; w < 33; w++) {
      float Av = ws[P_A + v * 33 + w];
      a0[w] = fmaf(Av, z0, a0[w]);
      a1[w] = fmaf(Av, z1, a1[w]);
    }
  }
  const float i10 = ws[i1O + oc], s10 = ws[b1O + oc];
  const float i11 = ws[i1O + oc + 32], s11 = ws[b1O + oc + 32];
#pragma unroll
  for (int w = 0; w < 33; w++) {
    zb[(tl * 33 + w) * 64 + oc]      = f2b(fmaxf(fmaf(a0[w], i10, s10), 0.f));
    zb[(tl * 33 + w) * 64 + oc + 32] = f2b(fmaxf(fmaf(a1[w], i11, s11), 0.f));
  }
  __syncthreads();
  short* dst = y + ((size_t)b * TV + rows0) * 64;
  for (int u = tid; u < 264 * 8; u += 256)
    *(v8s*)(dst + u * 8) = *(const v8s*)(zb + u * 8);
}

// ---------------- tcn: temporal conv GEMM + folded residual -----------------
// POOL: no global write; reduce relu(bn2) over pixels -> atomicAdd feat[b][o].
template <int CI, int CO, int RSTRIDE, bool POOL>
__global__ __launch_bounds__(256, 2) void tcn_kern(
    const short* __restrict__ act, const short* __restrict__ res,
    const short* __restrict__ wfrag, const float* __restrict__ ws,
    short* __restrict__ out, float* __restrict__ feat, int sAO, int sBO) {
  constexpr int NT = CO / 16;
  constexpr int TAPS = 9;
  constexpr int H = 132, WIN = 520, RS = 40;
  constexpr int NCH = CI / 32;
  constexpr int RCH = (RSTRIDE == 64) ? 2 : 1;
  constexpr int TOT = NCH * TAPS + RCH;
  __shared__ __align__(16) short sw[WIN * RS];
  __shared__ float pool[4][64];
  const int tid = threadIdx.x;
  const int b = blockIdx.y;
  const int p0 = blockIdx.x * 256;
  const int lane = tid & 63, wv = tid >> 6;
  const int ln = lane & 15, q8 = (lane >> 4) * 8;
  const int wvbase = wv * 64;
  const v8s* wf = (const v8s*)wfrag;
  v4f acc[4][NT];
#pragma unroll
  for (int mt = 0; mt < 4; mt++)
#pragma unroll
    for (int nt = 0; nt < NT; nt++) acc[mt][nt] = (v4f){0.f, 0.f, 0.f, 0.f};

  v8s bcur[NT];
#pragma unroll
  for (int nt = 0; nt < NT; nt++) bcur[nt] = wf[nt * 64 + lane];

  const bool interior = (p0 >= H) && (p0 + 256 + H <= TV);

  for (int cc = 0; cc < NCH; cc++) {
    __syncthreads();
    const short* src = act + (size_t)b * TV * CI + cc * 32;
    if (interior) {
      for (int u = tid; u < WIN * 4; u += 256) {
        int off = u >> 2, c0 = (u & 3) * 8;
        *(v8s*)(sw + off * RS + c0) =
            *(const v8s*)(src + (size_t)(p0 - H + off) * CI + c0);
      }
    } else {
      for (int u = tid; u < WIN * 4; u += 256) {
        int off = u >> 2, c0 = (u & 3) * 8;
        int qp = p0 - H + off;
        v8s val = {0, 0, 0, 0, 0, 0, 0, 0};
        if (qp >= 0 && qp < TV) val = *(const v8s*)(src + (size_t)qp * CI + c0);
        *(v8s*)(sw + off * RS + c0) = val;
      }
    }
    __syncthreads();
    v8s acur[4];
#pragma unroll
    for (int mt = 0; mt < 4; mt++)
      acur[mt] = *(const v8s*)(sw + (wvbase + mt * 16 + ln) * RS + q8);
#pragma unroll
    for (int tap = 0; tap < TAPS; tap++) {
      int s = cc * TAPS + tap;
      int sn = (s + 1 < TOT) ? s + 1 : s;
      v8s bnx[NT];
#pragma unroll
      for (int nt = 0; nt < NT; nt++) bnx[nt] = wf[(sn * NT + nt) * 64 + lane];
      v8s anx[4];
      if (tap + 1 < TAPS) {
#pragma unroll
        for (int mt = 0; mt < 4; mt++)
          anx[mt] = *(const v8s*)(sw + (wvbase + mt * 16 + ln + (tap + 1) * 33) * RS + q8);
      }
#pragma unroll
      for (int mt = 0; mt < 4; mt++)
#pragma unroll
        for (int nt = 0; nt < NT; nt++)
          acc[mt][nt] = __builtin_amdgcn_mfma_f32_16x16x32_bf16(
              acur[mt], bcur[nt], acc[mt][nt], 0, 0, 0);
      if (tap + 1 < TAPS) {
#pragma unroll
        for (int mt = 0; mt < 4; mt++) acur[mt] = anx[mt];
      }
#pragma unroll
      for (int nt = 0; nt < NT; nt++) bcur[nt] = bnx[nt];
    }
  }
  // residual K-steps
  const short* rsrc = res + (size_t)b * TV * RSTRIDE;
  for (int rc = 0; rc < RCH; rc++) {
    __syncthreads();
    if constexpr (RSTRIDE == 8) {
      int off = tid;
      v8s val = *(const v8s*)(rsrc + (size_t)(p0 + off) * 8);
      v8s zz = {0, 0, 0, 0, 0, 0, 0, 0};
      *(v8s*)(sw + off * RS + 0) = val;
      *(v8s*)(sw + off * RS + 8) = zz;
      *(v8s*)(sw + off * RS + 16) = zz;
      *(v8s*)(sw + off * RS + 24) = zz;
    } else {
      for (int u = tid; u < 1024; u += 256) {
        int off = u >> 2, c0 = (u & 3) * 8;
        *(v8s*)(sw + off * RS + c0) =
            *(const v8s*)(rsrc + (size_t)(p0 + off) * RSTRIDE + rc * 32 + c0);
      }
    }
    __syncthreads();
    int s = NCH * TAPS + rc;
    int sn = (s + 1 < TOT) ? s + 1 : s;
    v8s bnx[NT];
#pragma unroll
    for (int nt = 0; nt < NT; nt++) bnx[nt] = wf[(sn * NT + nt) * 64 + lane];
    v8s afr[4];
#pragma unroll
    for (int mt = 0; mt < 4; mt++)
      afr[mt] = *(const v8s*)(sw + (wvbase + mt * 16 + ln) * RS + q8);
#pragma unroll
    for (int mt = 0; mt < 4; mt++)
#pragma unroll
      for (int nt = 0; nt < NT; nt++)
        acc[mt][nt] = __builtin_amdgcn_mfma_f32_16x16x32_bf16(
            afr[mt], bcur[nt], acc[mt][nt], 0, 0, 0);
#pragma unroll
    for (int nt = 0; nt < NT; nt++) bcur[nt] = bnx[nt];
  }
  // epilogue
  if constexpr (POOL) {
    float ps[NT];
#pragma unroll
    for (int nt = 0; nt < NT; nt++) {
      int o = nt * 16 + ln;
      float sA = ws[sAO + o], sB = ws[sBO + o];
      float sl = 0.f;
#pragma unroll
      for (int mt = 0; mt < 4; mt++)
#pragma unroll
        for (int r = 0; r < 4; r++)
          sl += fmaxf(fmaf(acc[mt][nt][r], sA, sB), 0.f);
      ps[nt] = sl;
    }
#pragma unroll
    for (int nt = 0; nt < NT; nt++) {
      ps[nt] += __shfl_xor(ps[nt], 16);
      ps[nt] += __shfl_xor(ps[nt], 32);
    }
    __syncthreads();   // sw no longer needed; pool reuse barrier
    if (lane < 16) {
#pragma unroll
      for (int nt = 0; nt < NT; nt++) pool[wv][nt * 16 + lane] = ps[nt];
    }
    __syncthreads();
    if (tid < 64)
      atomicAdd(&feat[b * 64 + tid],
                pool[0][tid] + pool[1][tid] + pool[2][tid] + pool[3][tid]);
  } else {
#pragma unroll
    for (int nt = 0; nt < NT; nt++) {
      int o = nt * 16 + ln;
      float sA = ws[sAO + o], sB = ws[sBO + o];
#pragma unroll
      for (int mt = 0; mt < 4; mt++)
#pragma unroll
        for (int r = 0; r < 4; r++) {
          int pm = wvbase + mt * 16 + (lane >> 4) * 4 + r;
          float val = fmaxf(fmaf(acc[mt][nt][r], sA, sB), 0.f);
          out[((size_t)b * TV + p0 + pm) * CO + o] = f2b(val);
        }
    }
  }
}

// ---------------- k4: FC ----------------------------------------------------
__global__ __launch_bounds__(128) void k4_kern(const float* __restrict__ ws,
                                               float* __restrict__ out) {
  const int b = blockIdx.x, tid = threadIdx.x;
  __shared__ float sf[64];
  if (tid < 64) sf[tid] = ws[P_FEAT + b * 64 + tid] * (1.f / 8448.f);
  __syncthreads();
  if (tid < 100) {
    float a = ws[P_FCB + tid];
#pragma unroll
    for (int o = 0; o < 64; o++) a = fmaf(ws[P_FCW + tid * 64 + o], sf[o], a);
    out[b * 100 + tid] = a;
  }
}

// ---------------- launch -----------------------------------------------------
extern "C" void kernel_launch(void* const* d_in, const int* in_sizes, int n_in,
                              void* d_out, int out_size, void* d_ws, size_t ws_size,
                              hipStream_t stream) {
  const float* xin = (const float*)d_in[0];
  float* wsf = (float*)d_ws;
  char* wsb = (char*)d_ws;
  short* frags = (short*)(wsb + FRAG_OFF);
  short* R0 = (short*)(wsb + PARAM_BYTES);
  short* R1 = R0 + HBUF;
  short* R2 = R1 + HBUF;
  // lifetimes: y0=R0[0,half), h0=R0[half,end) | xb=R1 start then y1=R1 | h1=R2 | y2=R0
  short* y0 = R0;
  short* h0 = R0 + HBUF / 2;
  short* xb = R1;
  short* y1 = R1;
  short* h1 = R2;
  short* y2 = R0;
  float* feat = wsf + P_FEAT;

  Ptrs ptrs;
  for (int i = 0; i < 48 && i < n_in; i++) ptrs.p[i] = (const float*)d_in[i];

  prep_kernel<<<6, 256, 0, stream>>>(ptrs, wsf, frags);

  dim3 gpm(32, NB), gtc(33, NB);
  pm0_kern<<<gpm, 256, 0, stream>>>(xin, wsf, y0, xb);
  tcn_kern<32, 32, 8, false><<<gtc, 256, 0, stream>>>(
      y0, xb, frags + FK2_0, wsf, h0, nullptr, P_I2_0, P_B2_0);
  pm_kern<32><<<gpm, 256, 0, stream>>>(h0, frags + FK1A1, wsf, y1, P_PB1, P_I1_1, P_B1_1);
  tcn_kern<64, 64, 32, false><<<gtc, 256, 0, stream>>>(
      y1, h0, frags + FK2_1, wsf, h1, nullptr, P_I2_1, P_B2_1);
  pm_kern<64><<<gpm, 256, 0, stream>>>(h1, frags + FK1A2, wsf, y2, P_PB2, P_I1_2, P_B1_2);
  tcn_kern<64, 64, 64, true><<<gtc, 256, 0, stream>>>(
      y2, h1, frags + FK2_2, wsf, nullptr, feat, P_I2_2, P_B2_2);
  k4_kern<<<NB, 128, 0, stream>>>(wsf, (float*)d_out);
}